// Round 1
// baseline (339.894 us; speedup 1.0000x reference)
//
#include <hip/hip_runtime.h>

#define B_ 2
#define S_ 2048
#define D_ 1024
#define H_ 16
#define M_ 4096

typedef unsigned short u16;
typedef unsigned int u32;
typedef short bf8 __attribute__((ext_vector_type(8)));
typedef float f4 __attribute__((ext_vector_type(4)));

#define MFMA16(a, b, c) __builtin_amdgcn_mfma_f32_16x16x32_bf16(a, b, c, 0, 0, 0)

__device__ __forceinline__ u16 f2b(float f) {
  u32 u = __builtin_bit_cast(u32, f);
  u += 0x7fffu + ((u >> 16) & 1);
  return (u16)(u >> 16);
}
__device__ __forceinline__ u32 pack2(float lo, float hi) {
  return (u32)f2b(lo) | ((u32)f2b(hi) << 16);
}
__device__ __forceinline__ float b2f(u16 h) {
  return __builtin_bit_cast(float, (u32)h << 16);
}

// Stage a 64x64 bf16 tile into LDS with XOR swizzle: logical (row, c16) lives at
// physical c16 ^ (row&7). 256 threads, 2 x 16B each, coalesced global reads.
__device__ __forceinline__ void stage64(u16* lds, const u16* __restrict__ src,
                                        int srcStride, int t) {
#pragma unroll
  for (int i = 0; i < 2; ++i) {
    int c = t + 256 * i;
    int row = c >> 3, col = c & 7;
    uint4 v = *(const uint4*)(src + (size_t)row * srcStride + col * 8);
    int dcol = col ^ (row & 7);
    *(uint4*)(lds + row * 64 + dcol * 8) = v;
  }
}

// Read one MFMA operand fragment (lane&15 = row, 8 contiguous k at chunk lane>>4),
// honoring the swizzle. Row stride = 64 bf16 (128B).
__device__ __forceinline__ bf8 ldA(const u16* lds, int rowBase, int kc, int lane) {
  int row = rowBase + (lane & 15);
  int c = (kc * 4 + (lane >> 4)) ^ (row & 7);
  return *(const bf8*)(lds + row * 64 + c * 8);
}

// ---------------- f32 -> bf16 flat convert ----------------
__global__ __launch_bounds__(256) void cvtk(const float* __restrict__ in,
                                            u16* __restrict__ out, int n) {
  int i = (blockIdx.x * 256 + threadIdx.x) * 8;
  if (i >= n) return;
  float4 a = *(const float4*)(in + i);
  float4 b = *(const float4*)(in + i + 4);
  uint4 o;
  o.x = pack2(a.x, a.y);
  o.y = pack2(a.z, a.w);
  o.z = pack2(b.x, b.y);
  o.w = pack2(b.z, b.w);
  *(uint4*)(out + i) = o;
}

// ------------- f32 [R][C] -> bf16 [C][R] transpose+convert (per z matrix) -------------
__global__ __launch_bounds__(256) void tcvt(const float* __restrict__ in,
                                            u16* __restrict__ out, int R, int C) {
  int rt = blockIdx.x, ct = blockIdx.y, z = blockIdx.z;
  in += (size_t)z * R * C;
  out += (size_t)z * R * C;
  __shared__ float tile[64][65];
  int t = threadIdx.x;
  int r = t >> 2, cc = (t & 3) * 16;
#pragma unroll
  for (int j = 0; j < 16; j += 4) {
    float4 v = *(const float4*)(in + (size_t)(rt * 64 + r) * C + ct * 64 + cc + j);
    tile[r][cc + j] = v.x;
    tile[r][cc + j + 1] = v.y;
    tile[r][cc + j + 2] = v.z;
    tile[r][cc + j + 3] = v.w;
  }
  __syncthreads();
  int c = t >> 2;
  u32 buf[8];
#pragma unroll
  for (int j = 0; j < 8; ++j)
    buf[j] = pack2(tile[cc + 2 * j][c], tile[cc + 2 * j + 1][c]);
  uint4* dst = (uint4*)(out + (size_t)(ct * 64 + c) * R + rt * 64 + cc);
  dst[0] = make_uint4(buf[0], buf[1], buf[2], buf[3]);
  dst[1] = make_uint4(buf[4], buf[5], buf[6], buf[7]);
}

// ------------- bf16 [2048][64] -> [64][2048] transpose (per z = (b,h)) -------------
__global__ __launch_bounds__(256) void tb16(const u16* __restrict__ in,
                                            u16* __restrict__ out) {
  int st = blockIdx.x, z = blockIdx.z;
  in += (size_t)z * S_ * 64;
  out += (size_t)z * 64 * S_;
  __shared__ u16 tile[64][72];  // 144B rows: keeps uint4 alignment, breaks bank aliasing
  int t = threadIdx.x;
#pragma unroll
  for (int i = 0; i < 2; ++i) {
    int c = t + 256 * i;
    int row = c >> 3, col = (c & 7) * 8;
    uint4 v = *(const uint4*)(in + (size_t)(st * 64 + row) * 64 + col);
    *(uint4*)&tile[row][col] = v;
  }
  __syncthreads();
  int dv = t >> 2, cc = (t & 3) * 16;
  u32 buf[8];
#pragma unroll
  for (int j = 0; j < 8; ++j) {
    u16 a = tile[cc + 2 * j][dv];
    u16 b = tile[cc + 2 * j + 1][dv];
    buf[j] = (u32)a | ((u32)b << 16);
  }
  uint4* dst = (uint4*)(out + (size_t)dv * S_ + st * 64 + cc);
  dst[0] = make_uint4(buf[0], buf[1], buf[2], buf[3]);
  dst[1] = make_uint4(buf[4], buf[5], buf[6], buf[7]);
}

// ------------- per-head projection GEMM: [4096x1024] @ Wt[h] -> [B][H][S][64] -------------
__global__ __launch_bounds__(256) void proj_k(const u16* __restrict__ A,
                                              const u16* __restrict__ BT,
                                              const float* __restrict__ bias,
                                              u16* __restrict__ outp, float scale) {
  int mt = blockIdx.x, h = blockIdx.y;
  int t = threadIdx.x, lane = t & 63, w = t >> 6;
  int quad = lane >> 4, col = lane & 15;
  __shared__ u16 Asm[64 * 64], Bsm[64 * 64];
  f4 acc[4] = {};
  const u16* Abase = A + (size_t)(mt * 64) * 1024;
  const u16* Bbase = BT + (size_t)h * 64 * 1024;
  for (int kt = 0; kt < 16; ++kt) {
    __syncthreads();
    stage64(Asm, Abase + kt * 64, 1024, t);
    stage64(Bsm, Bbase + kt * 64, 1024, t);
    __syncthreads();
    bf8 a0 = ldA(Asm, w * 16, 0, lane);
    bf8 a1 = ldA(Asm, w * 16, 1, lane);
#pragma unroll
    for (int nf = 0; nf < 4; ++nf) {
      bf8 b0 = ldA(Bsm, nf * 16, 0, lane);
      bf8 b1 = ldA(Bsm, nf * 16, 1, lane);
      acc[nf] = MFMA16(a0, b0, acc[nf]);
      acc[nf] = MFMA16(a1, b1, acc[nf]);
    }
  }
#pragma unroll
  for (int nf = 0; nf < 4; ++nf) {
    int n = nf * 16 + col;
    float bs = bias[h * 64 + n];
#pragma unroll
    for (int r = 0; r < 4; ++r) {
      int gm = mt * 64 + w * 16 + quad * 4 + r;
      int bb = gm >> 11, s = gm & 2047;
      outp[(size_t)((bb * H_ + h) * S_ + s) * 64 + n] = f2b((acc[nf][r] + bs) * scale);
    }
  }
}

// ------------- output GEMM: ctx[4096x1024] @ WmT -> f32 out -------------
__global__ __launch_bounds__(256) void gemmo(const u16* __restrict__ A,
                                             const u16* __restrict__ BT,
                                             const float* __restrict__ bias,
                                             float* __restrict__ outp) {
  int mt = blockIdx.x, nt = blockIdx.y;
  int t = threadIdx.x, lane = t & 63, w = t >> 6;
  int quad = lane >> 4, col = lane & 15;
  __shared__ u16 Asm[64 * 64], Bsm[64 * 64];
  f4 acc[4] = {};
  for (int kt = 0; kt < 16; ++kt) {
    __syncthreads();
    stage64(Asm, A + (size_t)(mt * 64) * 1024 + kt * 64, 1024, t);
    stage64(Bsm, BT + (size_t)(nt * 64) * 1024 + kt * 64, 1024, t);
    __syncthreads();
    bf8 a0 = ldA(Asm, w * 16, 0, lane);
    bf8 a1 = ldA(Asm, w * 16, 1, lane);
#pragma unroll
    for (int nf = 0; nf < 4; ++nf) {
      bf8 b0 = ldA(Bsm, nf * 16, 0, lane);
      bf8 b1 = ldA(Bsm, nf * 16, 1, lane);
      acc[nf] = MFMA16(a0, b0, acc[nf]);
      acc[nf] = MFMA16(a1, b1, acc[nf]);
    }
  }
#pragma unroll
  for (int nf = 0; nf < 4; ++nf) {
    int n = nt * 64 + nf * 16 + col;
    float bs = bias[n];
#pragma unroll
    for (int r = 0; r < 4; ++r) {
      int gm = mt * 64 + w * 16 + quad * 4 + r;
      outp[(size_t)gm * 1024 + n] = acc[nf][r] + bs;
    }
  }
}

__device__ __forceinline__ void qk_tile(const u16* Ksm, bf8 qf0, bf8 qf1, int lane,
                                        f4 sc[4]) {
#pragma unroll
  for (int fr = 0; fr < 4; ++fr) {
    bf8 k0 = ldA(Ksm, fr * 16, 0, lane);
    bf8 k1 = ldA(Ksm, fr * 16, 1, lane);
    sc[fr] = MFMA16(k0, qf0, sc[fr]);
    sc[fr] = MFMA16(k1, qf1, sc[fr]);
  }
}

// ------------- fused attention: QK^T (swapped), 2-pass online softmax, P write, PV -------------
__global__ __launch_bounds__(256) void attn_k(const u16* __restrict__ qp,
                                              const u16* __restrict__ kp,
                                              const u16* __restrict__ vT,
                                              u16* __restrict__ ctxo,
                                              float* __restrict__ attw) {
  int qt = blockIdx.x, h = blockIdx.y, b = blockIdx.z;
  int t = threadIdx.x, lane = t & 63, w = t >> 6;
  int quad = lane >> 4, col = lane & 15;
  __shared__ u16 Qsm[64 * 64], Ksm[64 * 64], Vsm[64 * 64];
  __shared__ u16 Psm[4][16 * 64];

  const u16* qbase = qp + ((size_t)(b * H_ + h) * S_ + qt * 64) * 64;
  const u16* kbase = kp + (size_t)(b * H_ + h) * S_ * 64;
  const u16* vbase = vT + (size_t)(b * H_ + h) * 64 * S_;

  stage64(Qsm, qbase, 64, t);
  __syncthreads();
  // hoist this wave's 16 q-rows as B-operand fragments (q pre-scaled by 1/8)
  bf8 qf0 = ldA(Qsm, w * 16, 0, lane);
  bf8 qf1 = ldA(Qsm, w * 16, 1, lane);

  // ---- pass 1: per-lane online (max, sumexp) over this lane's key subset ----
  float m = -1e30f, l = 0.f;
  for (int kt = 0; kt < 32; ++kt) {
    __syncthreads();
    stage64(Ksm, kbase + (size_t)kt * 64 * 64, 64, t);
    __syncthreads();
    f4 sc[4] = {};
    qk_tile(Ksm, qf0, qf1, lane, sc);
    float mx = -1e30f;
#pragma unroll
    for (int fr = 0; fr < 4; ++fr)
#pragma unroll
      for (int r = 0; r < 4; ++r) mx = fmaxf(mx, sc[fr][r]);
    if (mx > m) {
      l *= __expf(m - mx);
      m = mx;
    }
    float ssum = 0.f;
#pragma unroll
    for (int fr = 0; fr < 4; ++fr)
#pragma unroll
      for (int r = 0; r < 4; ++r) ssum += __expf(sc[fr][r] - m);
    l += ssum;
  }
  // combine the 4 quadrant-lanes sharing the same q (lane&15)
#pragma unroll
  for (int off = 16; off <= 32; off <<= 1) {
    float mo = __shfl_xor(m, off);
    float lo = __shfl_xor(l, off);
    float mn = fmaxf(m, mo);
    l = l * __expf(m - mn) + lo * __expf(mo - mn);
    m = mn;
  }
  float linv = 1.f / l;

  // ---- pass 2: recompute S, write normalized P, accumulate ctx^T ----
  f4 ctxa[4] = {};
  u16* Pw = Psm[w];
  size_t awbase = ((size_t)(b * S_ + qt * 64 + w * 16) * H_ + h) * S_;
  for (int kt = 0; kt < 32; ++kt) {
    __syncthreads();
    stage64(Ksm, kbase + (size_t)kt * 64 * 64, 64, t);
    stage64(Vsm, vbase + kt * 64, S_, t);
    __syncthreads();
    f4 sc[4] = {};
    qk_tile(Ksm, qf0, qf1, lane, sc);
    // P strip [16 q][64 key] bf16, swizzled; lane writes its q=col row, keys quad*4+r+16*fr
#pragma unroll
    for (int fr = 0; fr < 4; ++fr) {
      float p0 = __expf(sc[fr][0] - m) * linv;
      float p1 = __expf(sc[fr][1] - m) * linv;
      float p2 = __expf(sc[fr][2] - m) * linv;
      float p3 = __expf(sc[fr][3] - m) * linv;
      int bo = col * 128 + ((fr * 32 + quad * 8) ^ ((col & 7) << 4));
      uint2 u;
      u.x = pack2(p0, p1);
      u.y = pack2(p2, p3);
      *(uint2*)((char*)Pw + bo) = u;
    }
    // PV: ctx^T[dv][q] += V^T[dv][key] * P[q][key]  (same-wave LDS dependency)
    bf8 pf0 = ldA(Pw, 0, 0, lane);
    bf8 pf1 = ldA(Pw, 0, 1, lane);
#pragma unroll
    for (int fr = 0; fr < 4; ++fr) {
      bf8 v0 = ldA(Vsm, fr * 16, 0, lane);
      bf8 v1 = ldA(Vsm, fr * 16, 1, lane);
      ctxa[fr] = MFMA16(v0, pf0, ctxa[fr]);
      ctxa[fr] = MFMA16(v1, pf1, ctxa[fr]);
    }
    // attention-weights f32 write, coalesced from the LDS strip
#pragma unroll
    for (int it = 0; it < 2; ++it) {
      int q = (lane >> 3) + 8 * it;
      int c16 = lane & 7;
      int bo = q * 128 + ((c16 ^ (q & 7)) << 4);
      bf8 pv = *(const bf8*)((const char*)Pw + bo);
      float* dst = attw + awbase + (size_t)q * (H_ * S_) + kt * 64 + c16 * 8;
      float4 o0, o1;
      o0.x = b2f((u16)pv[0]);
      o0.y = b2f((u16)pv[1]);
      o0.z = b2f((u16)pv[2]);
      o0.w = b2f((u16)pv[3]);
      o1.x = b2f((u16)pv[4]);
      o1.y = b2f((u16)pv[5]);
      o1.z = b2f((u16)pv[6]);
      o1.w = b2f((u16)pv[7]);
      *(float4*)dst = o0;
      *((float4*)dst + 1) = o1;
    }
  }
  // ctx epilogue: lane holds q=col, dv = fr*16 + quad*4 + r
  int qg = qt * 64 + w * 16 + col;
  size_t cb = ((size_t)(b * S_ + qg) * H_ + h) * 64;
#pragma unroll
  for (int fr = 0; fr < 4; ++fr) {
    uint2 u;
    u.x = pack2(ctxa[fr][0], ctxa[fr][1]);
    u.y = pack2(ctxa[fr][2], ctxa[fr][3]);
    *(uint2*)(ctxo + cb + fr * 16 + quad * 4) = u;
  }
}

extern "C" void kernel_launch(void* const* d_in, const int* in_sizes, int n_in,
                              void* d_out, int out_size, void* d_ws, size_t ws_size,
                              hipStream_t stream) {
  const float* Q = (const float*)d_in[0];
  const float* K = (const float*)d_in[1];
  const float* V = (const float*)d_in[2];
  const float* Wq = (const float*)d_in[3];
  const float* bq = (const float*)d_in[4];
  const float* Wk = (const float*)d_in[5];
  const float* bk = (const float*)d_in[6];
  const float* Wv = (const float*)d_in[7];
  const float* bv = (const float*)d_in[8];
  const float* Wm = (const float*)d_in[9];
  const float* bm = (const float*)d_in[10];
  float* out0 = (float*)d_out;
  float* out1 = out0 + (size_t)M_ * D_;

  u16* X = (u16*)d_ws;            // 4,194,304 elems (reused for Qb/Kb/Vb)
  u16* WT = X + 4194304;          // 1,048,576  (reused Wq/Wk/Wv/Wm transposed)
  u16* qp = WT + 1048576;         // 4,194,304  [B][H][S][64], pre-scaled 1/8
  u16* kp = qp + 4194304;         // 4,194,304
  u16* vp = kp + 4194304;         // 4,194,304  [B][H][S][64]; later reused as ctx
  u16* vTp = vp + 4194304;        // 4,194,304  [B][H][64][S]
  (void)in_sizes; (void)n_in; (void)out_size; (void)ws_size;

  const int NQKV = M_ * D_;

  // Q projection
  cvtk<<<2048, 256, 0, stream>>>(Q, X, NQKV);
  tcvt<<<dim3(16, 1, 16), 256, 0, stream>>>(Wq, WT, 1024, 64);
  proj_k<<<dim3(64, 16), 256, 0, stream>>>(X, WT, bq, qp, 0.125f);
  // K projection
  cvtk<<<2048, 256, 0, stream>>>(K, X, NQKV);
  tcvt<<<dim3(16, 1, 16), 256, 0, stream>>>(Wk, WT, 1024, 64);
  proj_k<<<dim3(64, 16), 256, 0, stream>>>(X, WT, bk, kp, 1.0f);
  // V projection
  cvtk<<<2048, 256, 0, stream>>>(V, X, NQKV);
  tcvt<<<dim3(16, 1, 16), 256, 0, stream>>>(Wv, WT, bv ? WT != nullptr ? 1024 : 1024 : 1024, 64);
  proj_k<<<dim3(64, 16), 256, 0, stream>>>(X, WT, bv, vp, 1.0f);
  // V transpose to [b][h][64][S]
  tb16<<<dim3(32, 1, 32), 256, 0, stream>>>(vp, vTp);
  // fused attention; ctx reuses vp
  attn_k<<<dim3(32, 16, 2), 256, 0, stream>>>(qp, kp, vTp, vp, out1);
  // output projection
  tcvt<<<dim3(16, 16, 1), 256, 0, stream>>>(Wm, WT, 1024, 1024);
  gemmo<<<dim3(64, 16), 256, 0, stream>>>(vp, WT, bm, out0);
}